// Round 9
// baseline (5792.920 us; speedup 1.0000x reference)
//
#include <hip/hip_runtime.h>

// ---------------------------------------------------------------------------
// LSTM (T=512, B=64, D=1024) + log_softmax projection.
//   1) convert_x:  x fp32 -> bf16
//   2) permute_w:  W_ih/W_hh -> bf16, gate-interleaved permutation
//   3) gemm_ih:    G[32768][4096] = Xb @ WihP^T + biasP  (MFMA, 128x128 tile)
//   4) lstm_grouped: P=4 batch-groups x C=64 col-blocks.
//      - W_hh slice in LDS, XOR-swizzled (128 KB)
//      - h exchange: publisher = atomic u64 stores (visible at L3);
//        consumer = per-step agent ACQUIRE FENCE (buffer_inv) + PLAIN
//        coalesced bf16x8 loads (atomics don't coalesce -> were ~1M
//        serialized L3 ops/step; plain loads are 16x fewer, wide, L2-shared)
//      - u16 per-block flags; poll = 16 lanes x u64; s_sleep backoff
//      - G stream non-temporal, prefetched after the fence (fence drains
//        vmcnt, so prefetch overlaps MFMA instead of the poll)
// ---------------------------------------------------------------------------

typedef float f32x4 __attribute__((ext_vector_type(4)));
typedef short bf16x8 __attribute__((ext_vector_type(8)));
typedef unsigned long long u64;

#define T_STEPS 512

__device__ inline unsigned short f2bf(float f) {
  unsigned u = __float_as_uint(f);
  u = u + 0x7FFFu + ((u >> 16) & 1u);
  return (unsigned short)(u >> 16);
}
__device__ inline float bf2f(unsigned short s) {
  return __uint_as_float(((unsigned)s) << 16);
}
__device__ inline float sigf(float x) { return 1.f / (1.f + __expf(-x)); }
__device__ inline float tanh_f(float x) {
  float e = __expf(-2.f * fabsf(x));
  float r = (1.f - e) / (1.f + e);
  return x >= 0.f ? r : -r;
}

// ---------------------------------------------------------------- convert_x
__global__ void convert_x(const float* __restrict__ x,
                          unsigned short* __restrict__ Xb, int n4) {
  int i = blockIdx.x * blockDim.x + threadIdx.x;
  const int stride = gridDim.x * blockDim.x;
  for (; i < n4; i += stride) {
    float4 v = ((const float4*)x)[i];
    ushort4 o;
    o.x = f2bf(v.x); o.y = f2bf(v.y); o.z = f2bf(v.z); o.w = f2bf(v.w);
    ((ushort4*)Xb)[i] = o;
  }
}

// ---------------------------------------------------------------- permute_w
// pcol = 16*i + 4*u + g  ->  orig row = g*1024 + 4*i + u   (unit = 4i+u)
__global__ void permute_w(const float* __restrict__ Wih,
                          const float* __restrict__ Whh,
                          const float* __restrict__ bih,
                          const float* __restrict__ bhh,
                          unsigned short* __restrict__ WihP,
                          unsigned short* __restrict__ WhhP,
                          float* __restrict__ biasP) {
  const int p = blockIdx.x;
  const int i = p >> 4, u = (p >> 2) & 3, g = p & 3;
  const int orig = g * 1024 + i * 4 + u;
  const int k = threadIdx.x * 4;
  float4 a = *(const float4*)(Wih + (size_t)orig * 1024 + k);
  ushort4 oa; oa.x = f2bf(a.x); oa.y = f2bf(a.y); oa.z = f2bf(a.z); oa.w = f2bf(a.w);
  *(ushort4*)(WihP + (size_t)p * 1024 + k) = oa;
  float4 b = *(const float4*)(Whh + (size_t)orig * 1024 + k);
  ushort4 ob; ob.x = f2bf(b.x); ob.y = f2bf(b.y); ob.z = f2bf(b.z); ob.w = f2bf(b.w);
  *(ushort4*)(WhhP + (size_t)p * 1024 + k) = ob;
  if (threadIdx.x == 0) biasP[p] = bih[orig] + bhh[orig];
}

// ---------------------------------------------------------------- gemm_ih
__global__ __launch_bounds__(256, 2) void gemm_ih(
    const unsigned short* __restrict__ Xb,
    const unsigned short* __restrict__ WihP,
    const float* __restrict__ biasP,
    unsigned short* __restrict__ G) {
  __shared__ unsigned short Alds[128 * 64];
  __shared__ unsigned short Blds[128 * 64];
  const int tid = threadIdx.x, lane = tid & 63, wave = tid >> 6;
  const int mt = blockIdx.y, nt = blockIdx.x;
  const int wm = (wave >> 1) * 64, wn = (wave & 1) * 64;

  f32x4 acc[4][4];
  {
    f32x4 z = {0.f, 0.f, 0.f, 0.f};
#pragma unroll
    for (int m = 0; m < 4; ++m)
#pragma unroll
      for (int n = 0; n < 4; ++n) acc[m][n] = z;
  }

  const int srow = lane >> 3;
  const int schunk = (lane & 7) ^ srow;
  const int frow = lane & 15;
  const int kgrp = lane >> 4;

  for (int kt = 0; kt < 16; ++kt) {
    __syncthreads();
#pragma unroll
    for (int q = 0; q < 4; ++q) {
      const int rr = (wave * 4 + q) * 8 + srow;
      const unsigned short* ga =
          Xb + (size_t)(mt * 128 + rr) * 1024 + kt * 64 + schunk * 8;
      __builtin_amdgcn_global_load_lds(
          (const __attribute__((address_space(1))) void*)ga,
          (__attribute__((address_space(3))) void*)(Alds + (wave * 4 + q) * 512),
          16, 0, 0);
      const unsigned short* gb =
          WihP + (size_t)(nt * 128 + rr) * 1024 + kt * 64 + schunk * 8;
      __builtin_amdgcn_global_load_lds(
          (const __attribute__((address_space(1))) void*)gb,
          (__attribute__((address_space(3))) void*)(Blds + (wave * 4 + q) * 512),
          16, 0, 0);
    }
    __syncthreads();
#pragma unroll
    for (int kk = 0; kk < 2; ++kk) {
      bf16x8 av[4], bv[4];
      const int kb = kk * 32 + 8 * kgrp;
#pragma unroll
      for (int i = 0; i < 4; ++i) {
        const int ra = wm + 16 * i + frow;
        av[i] = *(const bf16x8*)(Alds + ra * 64 + (kb ^ ((ra & 7) << 3)));
        const int rb = wn + 16 * i + frow;
        bv[i] = *(const bf16x8*)(Blds + rb * 64 + (kb ^ ((rb & 7) << 3)));
      }
#pragma unroll
      for (int m = 0; m < 4; ++m)
#pragma unroll
        for (int n = 0; n < 4; ++n)
          acc[m][n] = __builtin_amdgcn_mfma_f32_16x16x32_bf16(
              av[m], bv[n], acc[m][n], 0, 0, 0);
    }
  }
  // epilogue: NON-TEMPORAL stores — keep the G stream out of L3/L2
#pragma unroll
  for (int n = 0; n < 4; ++n) {
    const int col = nt * 128 + wn + 16 * n + frow;
    const float bvv = biasP[col];
#pragma unroll
    for (int m = 0; m < 4; ++m) {
      const int row0 = mt * 128 + wm + 16 * m + kgrp * 4;
#pragma unroll
      for (int r = 0; r < 4; ++r)
        __builtin_nontemporal_store(
            f2bf(acc[m][n][r] + bvv),
            G + (size_t)(row0 + r) * 4096 + col);
    }
  }
}

// ---------------------------------------------------------------- recurrence
// Grid: 256 blocks = 4 batch-groups (p = bid>>6) x 64 col-blocks (c = bid&63).
// h exchange layout (bf16): h_ex[buf][p][slab 0..63][b 0..15][u 0..15],
// slab s holds units [16s,16s+16) — block c publishes slab c (512 B contig).
__global__ __launch_bounds__(256, 1) void lstm_grouped(
    const unsigned short* __restrict__ G,     // [T*64][4096] bf16 (permuted)
    const unsigned short* __restrict__ WhhP,  // [4096][1024] bf16 (permuted)
    unsigned short* __restrict__ hbuf,        // 2 x 4 x 16384 elem
    float* __restrict__ hfinal,               // [64][1024] f32
    const float* __restrict__ Wproj, const float* __restrict__ bproj,
    float* __restrict__ out,                  // [64][2]
    unsigned short* __restrict__ flags) {     // [4][64] u16 step flags
  __shared__ unsigned short Wlds[64 * 1024];  // 128 KB, XOR-swizzled
  __shared__ float Gbuf[4][16][68];           // 17 KB partials, conflict-free
  const int tid = threadIdx.x, lane = tid & 63, wave = tid >> 6;
  const int bid = blockIdx.x;
  const int p = bid >> 6, c = bid & 63;

  // stage W_hh slice: elem (r,k) -> Wlds[r*1024 + (k ^ ((r&7)<<3))]
  {
    const int r = tid >> 2, q = tid & 3;
    const unsigned short* src = WhhP + (size_t)(c * 64 + r) * 1024 + q * 256;
    unsigned short* dstb = Wlds + r * 1024;
    const int swz = (r & 7) << 3;
#pragma unroll
    for (int j = 0; j < 256; j += 8) {
      uint4 v = *(const uint4*)(src + j);
      *(uint4*)(dstb + ((q * 256 + j) ^ swz)) = v;
    }
  }

  const int ub = tid >> 4, uu = tid & 15;        // update: batch, unit
  const int lpb = 16 * (uu >> 2) + 4 * (uu & 3); // local pcol base (g=0)
  const int frow = lane & 15, kgrp = lane >> 4;
  const int wbase = wave * 256;                  // K split across waves
  const u64* fq = (const u64*)(flags + p * 64) + (lane & 15);  // 4 flags/lane

  // per-lane h-read base (elements): slab = wave*16 + 2*kw + (kgrp>>1)
  const int hrd_base =
      wave * 4096 + (kgrp >> 1) * 256 + frow * 16 + (kgrp & 1) * 8;

  float c_state = 0.f;
  ushort4 gcur;
  {
    union { u64 q; ushort4 v; } ug;
    ug.q = __builtin_nontemporal_load(
        (const u64*)(G + (size_t)(p * 16 + ub) * 4096 + c * 64 + lpb));
    gcur = ug.v;
  }
  __syncthreads();

  for (int t = 0; t < T_STEPS; ++t) {
    const unsigned short* hread = hbuf + (size_t)(t & 1) * 65536 + p * 16384;
    unsigned short* hwrite =
        hbuf + (size_t)((t + 1) & 1) * 65536 + p * 16384;

    // poll: wave0 lanes 0..15, each checks 4 u16 flags via one u64 load
    if (wave == 0 && lane < 16) {
      unsigned guard = 0;
      while (true) {
        u64 q = __hip_atomic_load(fq, __ATOMIC_RELAXED,
                                  __HIP_MEMORY_SCOPE_AGENT);
        unsigned m0 = (unsigned)(q & 0xFFFFu);
        unsigned m1 = (unsigned)((q >> 16) & 0xFFFFu);
        unsigned m2 = (unsigned)((q >> 32) & 0xFFFFu);
        unsigned m3 = (unsigned)((q >> 48) & 0xFFFFu);
        unsigned mn = min(min(m0, m1), min(m2, m3));
        if (__all(mn >= (unsigned)t)) break;
        __builtin_amdgcn_s_sleep(1);
        if (++guard > (1u << 22)) break;  // liveness escape
      }
    }
    __syncthreads();  // B1: flags observed

    // acquire: invalidate stale L1/L2 h lines (cross-XCD non-coherence)
    __builtin_amdgcn_fence(__ATOMIC_ACQUIRE, "agent");

    // prefetch next-step G non-temporal AFTER the fence (fence drains vmcnt;
    // this overlaps MFMA/reduce instead — consumed only next iteration)
    ushort4 gnext = gcur;
    if (t + 1 < T_STEPS) {
      union { u64 q; ushort4 v; } ug;
      ug.q = __builtin_nontemporal_load(
          (const u64*)(G + (size_t)((t + 1) * 64 + p * 16 + ub) * 4096 +
                       c * 64 + lpb));
      gnext = ug.v;
    }

    // h loads: PLAIN coalesced 16B/lane (wave covers 2 slabs per kw)
    f32x4 acc[4];
    {
      f32x4 z = {0.f, 0.f, 0.f, 0.f};
      acc[0] = z; acc[1] = z; acc[2] = z; acc[3] = z;
    }
    bf16x8 av[8];
    {
      const unsigned short* abase = hread + hrd_base;
#pragma unroll
      for (int kw = 0; kw < 8; ++kw)
        av[kw] = *(const bf16x8*)(abase + kw * 512);
    }
#pragma unroll
    for (int kw = 0; kw < 8; ++kw) {
      const int k = wbase + kw * 32 + 8 * kgrp;
#pragma unroll
      for (int n = 0; n < 4; ++n) {
        const int pcol = n * 16 + frow;
        bf16x8 bv =
            *(const bf16x8*)(Wlds + pcol * 1024 + (k ^ ((pcol & 7) << 3)));
        acc[n] = __builtin_amdgcn_mfma_f32_16x16x32_bf16(av[kw], bv, acc[n],
                                                         0, 0, 0);
      }
    }

    // K-partials: Gbuf[wave][batch][pcol] (pad 68; conflict-free)
    {
      float* gp = &Gbuf[wave][0][0];
#pragma unroll
      for (int n = 0; n < 4; ++n)
#pragma unroll
        for (int r = 0; r < 4; ++r)
          gp[(4 * kgrp + r) * 68 + n * 16 + frow] = acc[n][r];
    }
    __syncthreads();  // B2: partials ready

    // reduce + pointwise (thread = batch ub x unit uu); u64 packed publish
    {
      f32x4 g4 = *(const f32x4*)(&Gbuf[0][ub][lpb]);
#pragma unroll
      for (int w = 1; w < 4; ++w) {
        f32x4 gw = *(const f32x4*)(&Gbuf[w][ub][lpb]);
        g4.x += gw.x; g4.y += gw.y; g4.z += gw.z; g4.w += gw.w;
      }
      const unsigned short* gc = (const unsigned short*)&gcur;
      const float ig = sigf(g4.x + bf2f(gc[0]));
      const float fg = sigf(g4.y + bf2f(gc[1]));
      const float gg = tanh_f(g4.z + bf2f(gc[2]));
      const float og = sigf(g4.w + bf2f(gc[3]));
      c_state = fg * c_state + ig * gg;
      const float hv = og * tanh_f(c_state);
      const unsigned hb = (unsigned)f2bf(hv);
      const unsigned b1 = (unsigned)__shfl_down((int)hb, 1);
      const unsigned b2 = (unsigned)__shfl_down((int)hb, 2);
      const unsigned b3 = (unsigned)__shfl_down((int)hb, 3);
      if (t == T_STEPS - 1)
        __hip_atomic_store(
            (unsigned*)(hfinal + (size_t)(p * 16 + ub) * 1024 + c * 16 + uu),
            __float_as_uint(hv), __ATOMIC_RELAXED, __HIP_MEMORY_SCOPE_AGENT);
      if ((uu & 3) == 0) {
        const u64 pk = (u64)(hb | (b1 << 16)) | ((u64)(b2 | (b3 << 16)) << 32);
        // slab c, row ub, units uu..uu+3 (contiguous 512B slab per block)
        __hip_atomic_store((u64*)(hwrite + c * 256 + ub * 16 + uu), pk,
                           __ATOMIC_RELAXED, __HIP_MEMORY_SCOPE_AGENT);
      }
      gcur = gnext;
    }
    // release: own-wave drain, then B3 (all waves drained), then one flag
    asm volatile("s_waitcnt vmcnt(0)" ::: "memory");
    __syncthreads();  // B3
    if (tid == 0)
      __hip_atomic_store(flags + p * 64 + c, (unsigned short)(t + 1),
                         __ATOMIC_RELAXED, __HIP_MEMORY_SCOPE_AGENT);
  }

  // ------------------------------------------------ projection (c==0 blocks)
  if (c == 0) {
    if (wave == 0 && lane < 16) {
      unsigned guard = 0;
      while (true) {
        u64 q = __hip_atomic_load(fq, __ATOMIC_RELAXED,
                                  __HIP_MEMORY_SCOPE_AGENT);
        unsigned m0 = (unsigned)(q & 0xFFFFu);
        unsigned m1 = (unsigned)((q >> 16) & 0xFFFFu);
        unsigned m2 = (unsigned)((q >> 32) & 0xFFFFu);
        unsigned m3 = (unsigned)((q >> 48) & 0xFFFFu);
        unsigned mn = min(min(m0, m1), min(m2, m3));
        if (__all(mn >= (unsigned)T_STEPS)) break;
        __builtin_amdgcn_s_sleep(1);
        if (++guard > (1u << 22)) break;
      }
    }
    __syncthreads();
    __builtin_amdgcn_fence(__ATOMIC_ACQUIRE, "agent");
    const int b = tid >> 4, seg = tid & 15;
    const float* hf = hfinal + (size_t)(p * 16 + b) * 1024 + seg * 64;
    const float* w0 = Wproj + seg * 64;
    const float* w1 = Wproj + 1024 + seg * 64;
    float s0 = 0.f, s1 = 0.f;
    for (int k = 0; k < 64; k += 2) {
      float2 hv2 = *(const float2*)(hf + k);
      float2 wv0 = *(const float2*)(w0 + k);
      float2 wv1 = *(const float2*)(w1 + k);
      s0 += hv2.x * wv0.x + hv2.y * wv0.y;
      s1 += hv2.x * wv1.x + hv2.y * wv1.y;
    }
#pragma unroll
    for (int off = 8; off > 0; off >>= 1) {
      s0 += __shfl_down(s0, off, 16);
      s1 += __shfl_down(s1, off, 16);
    }
    if (seg == 0) {
      s0 += bproj[0];
      s1 += bproj[1];
      const float mx = fmaxf(s0, s1);
      const float lse = mx + logf(expf(s0 - mx) + expf(s1 - mx));
      out[(p * 16 + b) * 2 + 0] = s0 - lse;
      out[(p * 16 + b) * 2 + 1] = s1 - lse;
    }
  }
}

// ---------------------------------------------------------------- launcher
extern "C" void kernel_launch(void* const* d_in, const int* in_sizes, int n_in,
                              void* d_out, int out_size, void* d_ws,
                              size_t ws_size, hipStream_t stream) {
  const float* x = (const float*)d_in[0];
  const float* Wih = (const float*)d_in[1];
  const float* Whh = (const float*)d_in[2];
  const float* bih = (const float*)d_in[3];
  const float* bhh = (const float*)d_in[4];
  const float* Wproj = (const float*)d_in[5];
  const float* bproj = (const float*)d_in[6];
  float* out = (float*)d_out;

  const size_t OFF_G = 0;                  // 268435456
  const size_t OFF_XB = 268435456;         // 67108864
  const size_t OFF_WIH = 335544320;        // 8388608
  const size_t OFF_WHH = 343932928;        // 8388608
  const size_t OFF_BIAS = 352321536;       // 16384
  const size_t OFF_H = 352337920;          // 262144 (double buffer)
  const size_t OFF_HF = 352600064;         // 262144
  const size_t OFF_SYNC = 352862208;       // 4096
  const size_t TOTAL = 352866304;

  if (ws_size < TOTAL) {
    (void)hipMemsetAsync(d_out, 0, (size_t)out_size * sizeof(float), stream);
    return;
  }
  char* ws = (char*)d_ws;
  unsigned short* G = (unsigned short*)(ws + OFF_G);
  unsigned short* Xb = (unsigned short*)(ws + OFF_XB);
  unsigned short* WihP = (unsigned short*)(ws + OFF_WIH);
  unsigned short* WhhP = (unsigned short*)(ws + OFF_WHH);
  float* biasP = (float*)(ws + OFF_BIAS);
  unsigned short* hbuf = (unsigned short*)(ws + OFF_H);
  float* hfinal = (float*)(ws + OFF_HF);
  unsigned short* flags = (unsigned short*)(ws + OFF_SYNC);

  (void)hipMemsetAsync(hbuf, 0, 262144, stream);
  (void)hipMemsetAsync(flags, 0, 4096, stream);

  convert_x<<<2048, 256, 0, stream>>>(x, Xb, 512 * 64 * 1024 / 4);
  permute_w<<<4096, 256, 0, stream>>>(Wih, Whh, bih, bhh, WihP, WhhP, biasP);
  gemm_ih<<<dim3(32, 256), 256, 0, stream>>>(Xb, WihP, biasP, G);
  lstm_grouped<<<256, 256, 0, stream>>>(G, WhhP, hbuf, hfinal, Wproj, bproj,
                                        out, flags);
}

// Round 10
// 2269.322 us; speedup vs baseline: 2.5527x; 2.5527x over previous
//
#include <hip/hip_runtime.h>

// ---------------------------------------------------------------------------
// LSTM (T=512, B=64, D=1024) + log_softmax projection.
//   1) convert_x:  x fp32 -> bf16
//   2) permute_w:  W_ih/W_hh -> bf16, gate-interleaved permutation
//   3) gemm_ih:    G[32768][4096] = Xb @ WihP^T + biasP  (MFMA, 128x128 tile)
//   4) lstm_grouped: P=4 batch-groups x C=64 col-blocks.
//      - W_hh slice in LDS, XOR-swizzled (128 KB)
//      - h exchange: publisher = atomic u64 stores (sc1, visible at L3);
//        consumer = PLAIN global_load_dwordx4 with sc1 policy via inline asm
//        (same coherence bits the compiler emits for AGENT atomics, but on
//        the normal vector path -> full wave coalescing, ~8x fewer TCC ops
//        than 8B atomic loads). No fences anywhere (R9 showed buffer_inv
//        per step costs +6.5us/step).
//      - u16 per-block flags; poll = 16 lanes x u64; s_sleep backoff
//      - G stream non-temporal, prefetched before the poll
// ---------------------------------------------------------------------------

typedef float f32x4 __attribute__((ext_vector_type(4)));
typedef short bf16x8 __attribute__((ext_vector_type(8)));
typedef unsigned long long u64;

#define T_STEPS 512

__device__ inline unsigned short f2bf(float f) {
  unsigned u = __float_as_uint(f);
  u = u + 0x7FFFu + ((u >> 16) & 1u);
  return (unsigned short)(u >> 16);
}
__device__ inline float bf2f(unsigned short s) {
  return __uint_as_float(((unsigned)s) << 16);
}
__device__ inline float sigf(float x) { return 1.f / (1.f + __expf(-x)); }
__device__ inline float tanh_f(float x) {
  float e = __expf(-2.f * fabsf(x));
  float r = (1.f - e) / (1.f + e);
  return x >= 0.f ? r : -r;
}

// coherent (agent/L3) 16B load on the coalescing vector path: sc1 = L1/L2
// bypass, exactly the policy the compiler uses for AGENT-scope atomic loads.
__device__ inline bf16x8 load_h16_sc1(const unsigned short* p) {
  bf16x8 r;
  asm volatile("global_load_dwordx4 %0, %1, off sc1"
               : "=v"(r)
               : "v"((u64)p));
  return r;
}

// ---------------------------------------------------------------- convert_x
__global__ void convert_x(const float* __restrict__ x,
                          unsigned short* __restrict__ Xb, int n4) {
  int i = blockIdx.x * blockDim.x + threadIdx.x;
  const int stride = gridDim.x * blockDim.x;
  for (; i < n4; i += stride) {
    float4 v = ((const float4*)x)[i];
    ushort4 o;
    o.x = f2bf(v.x); o.y = f2bf(v.y); o.z = f2bf(v.z); o.w = f2bf(v.w);
    ((ushort4*)Xb)[i] = o;
  }
}

// ---------------------------------------------------------------- permute_w
// pcol = 16*i + 4*u + g  ->  orig row = g*1024 + 4*i + u   (unit = 4i+u)
__global__ void permute_w(const float* __restrict__ Wih,
                          const float* __restrict__ Whh,
                          const float* __restrict__ bih,
                          const float* __restrict__ bhh,
                          unsigned short* __restrict__ WihP,
                          unsigned short* __restrict__ WhhP,
                          float* __restrict__ biasP) {
  const int p = blockIdx.x;
  const int i = p >> 4, u = (p >> 2) & 3, g = p & 3;
  const int orig = g * 1024 + i * 4 + u;
  const int k = threadIdx.x * 4;
  float4 a = *(const float4*)(Wih + (size_t)orig * 1024 + k);
  ushort4 oa; oa.x = f2bf(a.x); oa.y = f2bf(a.y); oa.z = f2bf(a.z); oa.w = f2bf(a.w);
  *(ushort4*)(WihP + (size_t)p * 1024 + k) = oa;
  float4 b = *(const float4*)(Whh + (size_t)orig * 1024 + k);
  ushort4 ob; ob.x = f2bf(b.x); ob.y = f2bf(b.y); ob.z = f2bf(b.z); ob.w = f2bf(b.w);
  *(ushort4*)(WhhP + (size_t)p * 1024 + k) = ob;
  if (threadIdx.x == 0) biasP[p] = bih[orig] + bhh[orig];
}

// ---------------------------------------------------------------- gemm_ih
__global__ __launch_bounds__(256, 2) void gemm_ih(
    const unsigned short* __restrict__ Xb,
    const unsigned short* __restrict__ WihP,
    const float* __restrict__ biasP,
    unsigned short* __restrict__ G) {
  __shared__ unsigned short Alds[128 * 64];
  __shared__ unsigned short Blds[128 * 64];
  const int tid = threadIdx.x, lane = tid & 63, wave = tid >> 6;
  const int mt = blockIdx.y, nt = blockIdx.x;
  const int wm = (wave >> 1) * 64, wn = (wave & 1) * 64;

  f32x4 acc[4][4];
  {
    f32x4 z = {0.f, 0.f, 0.f, 0.f};
#pragma unroll
    for (int m = 0; m < 4; ++m)
#pragma unroll
      for (int n = 0; n < 4; ++n) acc[m][n] = z;
  }

  const int srow = lane >> 3;
  const int schunk = (lane & 7) ^ srow;
  const int frow = lane & 15;
  const int kgrp = lane >> 4;

  for (int kt = 0; kt < 16; ++kt) {
    __syncthreads();
#pragma unroll
    for (int q = 0; q < 4; ++q) {
      const int rr = (wave * 4 + q) * 8 + srow;
      const unsigned short* ga =
          Xb + (size_t)(mt * 128 + rr) * 1024 + kt * 64 + schunk * 8;
      __builtin_amdgcn_global_load_lds(
          (const __attribute__((address_space(1))) void*)ga,
          (__attribute__((address_space(3))) void*)(Alds + (wave * 4 + q) * 512),
          16, 0, 0);
      const unsigned short* gb =
          WihP + (size_t)(nt * 128 + rr) * 1024 + kt * 64 + schunk * 8;
      __builtin_amdgcn_global_load_lds(
          (const __attribute__((address_space(1))) void*)gb,
          (__attribute__((address_space(3))) void*)(Blds + (wave * 4 + q) * 512),
          16, 0, 0);
    }
    __syncthreads();
#pragma unroll
    for (int kk = 0; kk < 2; ++kk) {
      bf16x8 av[4], bv[4];
      const int kb = kk * 32 + 8 * kgrp;
#pragma unroll
      for (int i = 0; i < 4; ++i) {
        const int ra = wm + 16 * i + frow;
        av[i] = *(const bf16x8*)(Alds + ra * 64 + (kb ^ ((ra & 7) << 3)));
        const int rb = wn + 16 * i + frow;
        bv[i] = *(const bf16x8*)(Blds + rb * 64 + (kb ^ ((rb & 7) << 3)));
      }
#pragma unroll
      for (int m = 0; m < 4; ++m)
#pragma unroll
        for (int n = 0; n < 4; ++n)
          acc[m][n] = __builtin_amdgcn_mfma_f32_16x16x32_bf16(
              av[m], bv[n], acc[m][n], 0, 0, 0);
    }
  }
  // epilogue: NON-TEMPORAL stores — keep the G stream out of L3/L2
#pragma unroll
  for (int n = 0; n < 4; ++n) {
    const int col = nt * 128 + wn + 16 * n + frow;
    const float bvv = biasP[col];
#pragma unroll
    for (int m = 0; m < 4; ++m) {
      const int row0 = mt * 128 + wm + 16 * m + kgrp * 4;
#pragma unroll
      for (int r = 0; r < 4; ++r)
        __builtin_nontemporal_store(
            f2bf(acc[m][n][r] + bvv),
            G + (size_t)(row0 + r) * 4096 + col);
    }
  }
}

// ---------------------------------------------------------------- recurrence
// Grid: 256 blocks = 4 batch-groups (p = bid>>6) x 64 col-blocks (c = bid&63).
// h exchange layout (bf16): h_ex[buf][p][slab 0..63][b 0..15][u 0..15],
// slab s holds units [16s,16s+16) — block c publishes slab c (512 B contig).
__global__ __launch_bounds__(256, 1) void lstm_grouped(
    const unsigned short* __restrict__ G,     // [T*64][4096] bf16 (permuted)
    const unsigned short* __restrict__ WhhP,  // [4096][1024] bf16 (permuted)
    unsigned short* __restrict__ hbuf,        // 2 x 4 x 16384 elem
    float* __restrict__ hfinal,               // [64][1024] f32
    const float* __restrict__ Wproj, const float* __restrict__ bproj,
    float* __restrict__ out,                  // [64][2]
    unsigned short* __restrict__ flags) {     // [4][64] u16 step flags
  __shared__ unsigned short Wlds[64 * 1024];  // 128 KB, XOR-swizzled
  __shared__ float Gbuf[4][16][68];           // 17 KB partials, conflict-free
  const int tid = threadIdx.x, lane = tid & 63, wave = tid >> 6;
  const int bid = blockIdx.x;
  const int p = bid >> 6, c = bid & 63;

  // stage W_hh slice: elem (r,k) -> Wlds[r*1024 + (k ^ ((r&7)<<3))]
  {
    const int r = tid >> 2, q = tid & 3;
    const unsigned short* src = WhhP + (size_t)(c * 64 + r) * 1024 + q * 256;
    unsigned short* dstb = Wlds + r * 1024;
    const int swz = (r & 7) << 3;
#pragma unroll
    for (int j = 0; j < 256; j += 8) {
      uint4 v = *(const uint4*)(src + j);
      *(uint4*)(dstb + ((q * 256 + j) ^ swz)) = v;
    }
  }

  const int ub = tid >> 4, uu = tid & 15;        // update: batch, unit
  const int lpb = 16 * (uu >> 2) + 4 * (uu & 3); // local pcol base (g=0)
  const int frow = lane & 15, kgrp = lane >> 4;
  const int wbase = wave * 256;                  // K split across waves
  const u64* fq = (const u64*)(flags + p * 64) + (lane & 15);  // 4 flags/lane

  // per-lane h-read base (elements): slab = wave*16 + 2*kw + (kgrp>>1)
  const int hrd_base =
      wave * 4096 + (kgrp >> 1) * 256 + frow * 16 + (kgrp & 1) * 8;

  float c_state = 0.f;
  ushort4 gcur;
  {
    union { u64 q; ushort4 v; } ug;
    ug.q = __builtin_nontemporal_load(
        (const u64*)(G + (size_t)(p * 16 + ub) * 4096 + c * 64 + lpb));
    gcur = ug.v;
  }
  __syncthreads();

  for (int t = 0; t < T_STEPS; ++t) {
    const unsigned short* hread = hbuf + (size_t)(t & 1) * 65536 + p * 16384;
    unsigned short* hwrite =
        hbuf + (size_t)((t + 1) & 1) * 65536 + p * 16384;

    // prefetch next-step G non-temporal (overlaps the poll; G immutable)
    ushort4 gnext = gcur;
    if (t + 1 < T_STEPS) {
      union { u64 q; ushort4 v; } ug;
      ug.q = __builtin_nontemporal_load(
          (const u64*)(G + (size_t)((t + 1) * 64 + p * 16 + ub) * 4096 +
                       c * 64 + lpb));
      gnext = ug.v;
    }

    // poll: wave0 lanes 0..15, each checks 4 u16 flags via one u64 load
    if (wave == 0 && lane < 16) {
      unsigned guard = 0;
      while (true) {
        u64 q = __hip_atomic_load(fq, __ATOMIC_RELAXED,
                                  __HIP_MEMORY_SCOPE_AGENT);
        unsigned m0 = (unsigned)(q & 0xFFFFu);
        unsigned m1 = (unsigned)((q >> 16) & 0xFFFFu);
        unsigned m2 = (unsigned)((q >> 32) & 0xFFFFu);
        unsigned m3 = (unsigned)((q >> 48) & 0xFFFFu);
        unsigned mn = min(min(m0, m1), min(m2, m3));
        if (__all(mn >= (unsigned)t)) break;
        __builtin_amdgcn_s_sleep(1);
        if (++guard > (1u << 22)) break;  // liveness escape
      }
    }
    __syncthreads();  // B1: h(t) published & flags observed

    // h loads: coalesced 16B/lane, sc1 (L3-coherent, bypasses stale L1/L2)
    f32x4 acc[4];
    {
      f32x4 z = {0.f, 0.f, 0.f, 0.f};
      acc[0] = z; acc[1] = z; acc[2] = z; acc[3] = z;
    }
    bf16x8 av[8];
    {
      const unsigned short* abase = hread + hrd_base;
#pragma unroll
      for (int kw = 0; kw < 8; ++kw)
        av[kw] = load_h16_sc1(abase + kw * 512);
    }
    asm volatile("s_waitcnt vmcnt(0)" ::: "memory");
    __builtin_amdgcn_sched_barrier(0);  // rule #18: pin MFMA after the wait

#pragma unroll
    for (int kw = 0; kw < 8; ++kw) {
      const int k = wbase + kw * 32 + 8 * kgrp;
#pragma unroll
      for (int n = 0; n < 4; ++n) {
        const int pcol = n * 16 + frow;
        bf16x8 bv =
            *(const bf16x8*)(Wlds + pcol * 1024 + (k ^ ((pcol & 7) << 3)));
        acc[n] = __builtin_amdgcn_mfma_f32_16x16x32_bf16(av[kw], bv, acc[n],
                                                         0, 0, 0);
      }
    }

    // K-partials: Gbuf[wave][batch][pcol] (pad 68; conflict-free)
    {
      float* gp = &Gbuf[wave][0][0];
#pragma unroll
      for (int n = 0; n < 4; ++n)
#pragma unroll
        for (int r = 0; r < 4; ++r)
          gp[(4 * kgrp + r) * 68 + n * 16 + frow] = acc[n][r];
    }
    __syncthreads();  // B2: partials ready

    // reduce + pointwise (thread = batch ub x unit uu); u64 packed publish
    {
      f32x4 g4 = *(const f32x4*)(&Gbuf[0][ub][lpb]);
#pragma unroll
      for (int w = 1; w < 4; ++w) {
        f32x4 gw = *(const f32x4*)(&Gbuf[w][ub][lpb]);
        g4.x += gw.x; g4.y += gw.y; g4.z += gw.z; g4.w += gw.w;
      }
      const unsigned short* gc = (const unsigned short*)&gcur;
      const float ig = sigf(g4.x + bf2f(gc[0]));
      const float fg = sigf(g4.y + bf2f(gc[1]));
      const float gg = tanh_f(g4.z + bf2f(gc[2]));
      const float og = sigf(g4.w + bf2f(gc[3]));
      c_state = fg * c_state + ig * gg;
      const float hv = og * tanh_f(c_state);
      const unsigned hb = (unsigned)f2bf(hv);
      const unsigned b1 = (unsigned)__shfl_down((int)hb, 1);
      const unsigned b2 = (unsigned)__shfl_down((int)hb, 2);
      const unsigned b3 = (unsigned)__shfl_down((int)hb, 3);
      if (t == T_STEPS - 1)
        __hip_atomic_store(
            (unsigned*)(hfinal + (size_t)(p * 16 + ub) * 1024 + c * 16 + uu),
            __float_as_uint(hv), __ATOMIC_RELAXED, __HIP_MEMORY_SCOPE_AGENT);
      if ((uu & 3) == 0) {
        const u64 pk = (u64)(hb | (b1 << 16)) | ((u64)(b2 | (b3 << 16)) << 32);
        // slab c, row ub, units uu..uu+3 (contiguous 512B slab per block)
        __hip_atomic_store((u64*)(hwrite + c * 256 + ub * 16 + uu), pk,
                           __ATOMIC_RELAXED, __HIP_MEMORY_SCOPE_AGENT);
      }
      gcur = gnext;
    }
    // release: own-wave drain, then B3 (all waves drained), then one flag
    asm volatile("s_waitcnt vmcnt(0)" ::: "memory");
    __syncthreads();  // B3
    if (tid == 0)
      __hip_atomic_store(flags + p * 64 + c, (unsigned short)(t + 1),
                         __ATOMIC_RELAXED, __HIP_MEMORY_SCOPE_AGENT);
  }

  // ------------------------------------------------ projection (c==0 blocks)
  if (c == 0) {
    if (wave == 0 && lane < 16) {
      unsigned guard = 0;
      while (true) {
        u64 q = __hip_atomic_load(fq, __ATOMIC_RELAXED,
                                  __HIP_MEMORY_SCOPE_AGENT);
        unsigned m0 = (unsigned)(q & 0xFFFFu);
        unsigned m1 = (unsigned)((q >> 16) & 0xFFFFu);
        unsigned m2 = (unsigned)((q >> 32) & 0xFFFFu);
        unsigned m3 = (unsigned)((q >> 48) & 0xFFFFu);
        unsigned mn = min(min(m0, m1), min(m2, m3));
        if (__all(mn >= (unsigned)T_STEPS)) break;
        __builtin_amdgcn_s_sleep(1);
        if (++guard > (1u << 22)) break;
      }
    }
    __syncthreads();
    const int b = tid >> 4, seg = tid & 15;
    const float* hf = hfinal + (size_t)(p * 16 + b) * 1024 + seg * 64;
    const float* w0 = Wproj + seg * 64;
    const float* w1 = Wproj + 1024 + seg * 64;
    float s0 = 0.f, s1 = 0.f;
    for (int k = 0; k < 64; k += 2) {
      u64 hq = __hip_atomic_load((const u64*)(hf + k), __ATOMIC_RELAXED,
                                 __HIP_MEMORY_SCOPE_AGENT);
      union { u64 q; float f[2]; } uh;
      uh.q = hq;
      float2 wv0 = *(const float2*)(w0 + k);
      float2 wv1 = *(const float2*)(w1 + k);
      s0 += uh.f[0] * wv0.x + uh.f[1] * wv0.y;
      s1 += uh.f[0] * wv1.x + uh.f[1] * wv1.y;
    }
#pragma unroll
    for (int off = 8; off > 0; off >>= 1) {
      s0 += __shfl_down(s0, off, 16);
      s1 += __shfl_down(s1, off, 16);
    }
    if (seg == 0) {
      s0 += bproj[0];
      s1 += bproj[1];
      const float mx = fmaxf(s0, s1);
      const float lse = mx + logf(expf(s0 - mx) + expf(s1 - mx));
      out[(p * 16 + b) * 2 + 0] = s0 - lse;
      out[(p * 16 + b) * 2 + 1] = s1 - lse;
    }
  }
}

// ---------------------------------------------------------------- launcher
extern "C" void kernel_launch(void* const* d_in, const int* in_sizes, int n_in,
                              void* d_out, int out_size, void* d_ws,
                              size_t ws_size, hipStream_t stream) {
  const float* x = (const float*)d_in[0];
  const float* Wih = (const float*)d_in[1];
  const float* Whh = (const float*)d_in[2];
  const float* bih = (const float*)d_in[3];
  const float* bhh = (const float*)d_in[4];
  const float* Wproj = (const float*)d_in[5];
  const float* bproj = (const float*)d_in[6];
  float* out = (float*)d_out;

  const size_t OFF_G = 0;                  // 268435456
  const size_t OFF_XB = 268435456;         // 67108864
  const size_t OFF_WIH = 335544320;        // 8388608
  const size_t OFF_WHH = 343932928;        // 8388608
  const size_t OFF_BIAS = 352321536;       // 16384
  const size_t OFF_H = 352337920;          // 262144 (double buffer)
  const size_t OFF_HF = 352600064;         // 262144
  const size_t OFF_SYNC = 352862208;       // 4096
  const size_t TOTAL = 352866304;

  if (ws_size < TOTAL) {
    (void)hipMemsetAsync(d_out, 0, (size_t)out_size * sizeof(float), stream);
    return;
  }
  char* ws = (char*)d_ws;
  unsigned short* G = (unsigned short*)(ws + OFF_G);
  unsigned short* Xb = (unsigned short*)(ws + OFF_XB);
  unsigned short* WihP = (unsigned short*)(ws + OFF_WIH);
  unsigned short* WhhP = (unsigned short*)(ws + OFF_WHH);
  float* biasP = (float*)(ws + OFF_BIAS);
  unsigned short* hbuf = (unsigned short*)(ws + OFF_H);
  float* hfinal = (float*)(ws + OFF_HF);
  unsigned short* flags = (unsigned short*)(ws + OFF_SYNC);

  (void)hipMemsetAsync(hbuf, 0, 262144, stream);
  (void)hipMemsetAsync(flags, 0, 4096, stream);

  convert_x<<<2048, 256, 0, stream>>>(x, Xb, 512 * 64 * 1024 / 4);
  permute_w<<<4096, 256, 0, stream>>>(Wih, Whh, bih, bhh, WihP, WhhP, biasP);
  gemm_ih<<<dim3(32, 256), 256, 0, stream>>>(Xb, WihP, biasP, G);
  lstm_grouped<<<256, 256, 0, stream>>>(G, WhhP, hbuf, hfinal, Wproj, bproj,
                                        out, flags);
}